// Round 3
// baseline (139.899 us; speedup 1.0000x reference)
//
#include <hip/hip_runtime.h>
#include <hip/hip_cooperative_groups.h>
#include <math.h>

#ifndef M_PI
#define M_PI 3.14159265358979323846
#endif

namespace cg = cooperative_groups;

#define NPTS 8192
#define KCOMP 64
#define JT 256            // j-tile per block
#define IBLK 256          // i's per block (= block size)
#define NJB (NPTS / JT)   // 32 j-chunks
#define NIB (NPTS / IBLK) // 32 i-chunks

// Force the single-instruction hardware exp2 (v_exp_f32, ~1 ulp).
__device__ __forceinline__ float fexp2(float a) {
#if __has_builtin(__builtin_amdgcn_exp2f)
  return __builtin_amdgcn_exp2f(a);
#else
  float r;
  asm("v_exp_f32 %0, %1" : "=v"(r) : "v"(a));
  return r;
#endif
}

// One cooperative dispatch:
//  phase 1: block bx = (jb<<5)|ib computes KDE partial for (i-range, j-tile jb)
//           -> part[jb*NPTS + i]  (atomic-free), thread (0,0) zeroes out[0]
//  grid.sync()
//  phase 2: blocks 0..31 fold partials, compute softmax/mixture pdf, MSE-reduce.
__global__ __launch_bounds__(IBLK, 4) void fused_kernel(
    const float* __restrict__ x,
    const float* __restrict__ logits,
    const float* __restrict__ means,
    const float* __restrict__ log_vars,
    float* __restrict__ part,
    float* __restrict__ out) {
  cg::grid_group grid = cg::this_grid();
  __shared__ alignas(16) float xs[JT];
  __shared__ float sm[KCOMP], sa[KCOMP], sq[KCOMP], wsum[4];

  const int t  = threadIdx.x;
  const int bx = blockIdx.x;
  const int ib = bx & (NIB - 1);
  const int jb = bx >> 5;
  const int i  = ib * IBLK + t;

  // kern = exp(-0.5 d^2 / bw^2) = 2^(-(s*d)^2), s = sqrt(8192 * log2(e))
  const float s = sqrtf(8192.0f * 1.44269504088896340736f);
  xs[t] = x[jb * JT + t] * s;   // pre-scaled j-tile
  float u = x[i] * s;           // pre-scaled own point
  if (bx == 0 && t == 0) out[0] = 0.0f;
  __syncthreads();

  float acc0 = 0.f, acc1 = 0.f, acc2 = 0.f, acc3 = 0.f;
  const float4* xs4 = reinterpret_cast<const float4*>(xs);
#pragma unroll 4
  for (int jj = 0; jj < JT / 4; ++jj) {
    float4 v = xs4[jj];         // ds_read_b128, same-address broadcast
    float d0 = u - v.x;
    float d1 = u - v.y;
    float d2 = u - v.z;
    float d3 = u - v.w;
    acc0 += fexp2(-(d0 * d0));  // v_sub + v_mul(neg) + v_exp + v_add
    acc1 += fexp2(-(d1 * d1));
    acc2 += fexp2(-(d2 * d2));
    acc3 += fexp2(-(d3 * d3));
  }
  part[jb * NPTS + i] = (acc0 + acc1) + (acc2 + acc3);

  grid.sync();                  // all partials + out[0]=0 visible device-wide

  if (bx < NIB) {
    if (t < KCOMP) {            // wave 0: softmax over K=64 via shfl
      float l = logits[t];
      float m = l;
#pragma unroll
      for (int off = 32; off > 0; off >>= 1)
        m = fmaxf(m, __shfl_xor(m, off));
      float e = expf(l - m);
      float ssum = e;
#pragma unroll
      for (int off = 32; off > 0; off >>= 1)
        ssum += __shfl_xor(ssum, off);
      float w = e / ssum;
      float var = expf(log_vars[t]);
      sm[t] = means[t];
      sa[t] = w * rsqrtf(2.0f * (float)M_PI * var);  // amplitude
      sq[t] = 0.72134752044448170368f / var;         // 0.5*log2(e)/var
    }
    __syncthreads();

    const int i2 = bx * IBLK + t;
    float ds = 0.f;
#pragma unroll
    for (int jjb = 0; jjb < NJB; ++jjb)
      ds += part[jjb * NPTS + i2];
    // data_pdf = ds / (sqrt(2*pi)*bw*N), bw*N = 64
    const float inv_norm = 1.0f / (2.50662827463100050242f * 64.0f);
    float data = ds * inv_norm;

    const float xi = x[i2];
    float mix = 0.f;
#pragma unroll 8
    for (int k = 0; k < KCOMP; ++k) {
      float d = xi - sm[k];
      mix += sa[k] * fexp2(-(sq[k] * d) * d);
    }

    float diff = mix - data;
    float v = diff * diff;
#pragma unroll
    for (int off = 32; off > 0; off >>= 1)
      v += __shfl_xor(v, off);
    if ((t & 63) == 0) wsum[t >> 6] = v;
    __syncthreads();
    if (t == 0) atomicAdd(out, (wsum[0] + wsum[1]) + (wsum[2] + wsum[3]));
  }
}

extern "C" void kernel_launch(void* const* d_in, const int* in_sizes, int n_in,
                              void* d_out, int out_size, void* d_ws, size_t ws_size,
                              hipStream_t stream) {
  const float* x     = (const float*)d_in[0];
  const float* wl    = (const float*)d_in[1];
  const float* means = (const float*)d_in[2];
  const float* lv    = (const float*)d_in[3];
  float* out  = (float*)d_out;
  float* part = (float*)d_ws;   // 32 * 8192 floats = 1 MB, fully overwritten

  void* args[] = {(void*)&x, (void*)&wl, (void*)&means, (void*)&lv,
                  (void*)&part, (void*)&out};
  hipLaunchCooperativeKernel((const void*)fused_kernel,
                             dim3(NIB * NJB), dim3(IBLK), args, 0, stream);
}

// Round 4
// 82.486 us; speedup vs baseline: 1.6960x; 1.6960x over previous
//
#include <hip/hip_runtime.h>
#include <math.h>

#ifndef M_PI
#define M_PI 3.14159265358979323846
#endif

#define NPTS 8192
#define KCOMP 64
#define JT 256            // j-tile per block
#define IBLK 256          // i's per block (= block size)
#define NJB (NPTS / JT)   // 32 j-chunks
#define NIB (NPTS / IBLK) // 32 i-chunks

// Module-load zero-initialized; each launch adds EXACTLY 32 to each cell,
// so "last arriver" is (old & 31) == 31 on every call — no memset needed,
// no dependence on the 0xAA ws poison, invariant across graph replays.
__device__ int g_ctr1[NIB];
__device__ int g_ctr2;

// Force the single-instruction hardware exp2 (v_exp_f32, ~1 ulp).
__device__ __forceinline__ float fexp2(float a) {
#if __has_builtin(__builtin_amdgcn_exp2f)
  return __builtin_amdgcn_exp2f(a);
#else
  float r;
  asm("v_exp_f32 %0, %1" : "=v"(r) : "v"(a));
  return r;
#endif
}

// One regular dispatch, 1024 blocks:
//  phase 1: block bx=(jb<<5)|ib -> part[jb*NPTS + i] (atomic-free stores)
//  per-ib rendezvous: agent-scope ACQ_REL fetch_add on g_ctr1[ib];
//    last arriver folds partials + softmax/mixture + MSE partial -> msep[ib]
//  per-grid rendezvous: g_ctr2; last winner sums msep -> out[0] (plain store)
__global__ __launch_bounds__(IBLK, 4) void fused_kernel(
    const float* __restrict__ x,
    const float* __restrict__ logits,
    const float* __restrict__ means,
    const float* __restrict__ log_vars,
    float* __restrict__ part,    // [NJB][NPTS]
    float* __restrict__ msep,    // [NIB]
    float* __restrict__ out) {
  __shared__ alignas(16) float xs[JT];
  __shared__ float sm[KCOMP], sa[KCOMP], sq[KCOMP], wsum[4];
  __shared__ int sflag;

  const int t  = threadIdx.x;
  const int bx = blockIdx.x;
  const int ib = bx & (NIB - 1);
  const int jb = bx >> 5;
  const int i  = ib * IBLK + t;

  // kern = exp(-0.5 d^2 / bw^2) = 2^(-(s*d)^2), s = sqrt(8192 * log2(e))
  const float s = sqrtf(8192.0f * 1.44269504088896340736f);
  xs[t] = x[jb * JT + t] * s;   // pre-scaled j-tile
  float u = x[i] * s;           // pre-scaled own point
  __syncthreads();

  float acc0 = 0.f, acc1 = 0.f, acc2 = 0.f, acc3 = 0.f;
  const float4* xs4 = reinterpret_cast<const float4*>(xs);
#pragma unroll 4
  for (int jj = 0; jj < JT / 4; ++jj) {
    float4 v = xs4[jj];         // ds_read_b128, same-address broadcast
    float d0 = u - v.x;
    float d1 = u - v.y;
    float d2 = u - v.z;
    float d3 = u - v.w;
    acc0 += fexp2(-(d0 * d0));  // v_sub + v_mul(neg) + v_exp + v_add
    acc1 += fexp2(-(d1 * d1));
    acc2 += fexp2(-(d2 * d2));
    acc3 += fexp2(-(d3 * d3));
  }
  part[jb * NPTS + i] = (acc0 + acc1) + (acc2 + acc3);

  // Block barrier drains our stores (compiler emits waitcnt before s_barrier),
  // then t0's agent-scope RELEASE makes them device-visible.
  __syncthreads();
  if (t == 0) {
    int old = __hip_atomic_fetch_add(&g_ctr1[ib], 1,
                                     __ATOMIC_ACQ_REL, __HIP_MEMORY_SCOPE_AGENT);
    sflag = ((old & (NJB - 1)) == (NJB - 1));  // last arriver for this ib
  }
  __syncthreads();
  if (!sflag) return;

  // ---- winner: all 32 partials for ib are visible (acquire above) ----
  if (t < KCOMP) {              // wave 0: softmax over K=64 via shfl
    float l = logits[t];
    float m = l;
#pragma unroll
    for (int off = 32; off > 0; off >>= 1)
      m = fmaxf(m, __shfl_xor(m, off));
    float e = expf(l - m);
    float ssum = e;
#pragma unroll
    for (int off = 32; off > 0; off >>= 1)
      ssum += __shfl_xor(ssum, off);
    float w = e / ssum;
    float var = expf(log_vars[t]);
    sm[t] = means[t];
    sa[t] = w * rsqrtf(2.0f * (float)M_PI * var);  // amplitude
    sq[t] = 0.72134752044448170368f / var;         // 0.5*log2(e)/var
  }
  __syncthreads();

  float dsum = 0.f;
#pragma unroll
  for (int b = 0; b < NJB; ++b)
    dsum += part[b * NPTS + i];
  // data_pdf = dsum / (sqrt(2*pi)*bw*N), bw*N = 64
  const float inv_norm = 1.0f / (2.50662827463100050242f * 64.0f);
  float data = dsum * inv_norm;

  const float xi = x[i];
  float mix = 0.f;
#pragma unroll 8
  for (int k = 0; k < KCOMP; ++k) {
    float d = xi - sm[k];
    mix += sa[k] * fexp2(-(sq[k] * d) * d);
  }

  float diff = mix - data;
  float v = diff * diff;
#pragma unroll
  for (int off = 32; off > 0; off >>= 1)
    v += __shfl_xor(v, off);
  if ((t & 63) == 0) wsum[t >> 6] = v;
  __syncthreads();

  if (t == 0) {
    msep[ib] = (wsum[0] + wsum[1]) + (wsum[2] + wsum[3]);
    int old2 = __hip_atomic_fetch_add(&g_ctr2, 1,
                                      __ATOMIC_ACQ_REL, __HIP_MEMORY_SCOPE_AGENT);
    if ((old2 & (NIB - 1)) == (NIB - 1)) {   // last winner: final sum
      float tot = 0.f;
      for (int b = 0; b < NIB; ++b)
        tot += msep[b];
      out[0] = tot;                          // plain store overwrites poison
    }
  }
}

extern "C" void kernel_launch(void* const* d_in, const int* in_sizes, int n_in,
                              void* d_out, int out_size, void* d_ws, size_t ws_size,
                              hipStream_t stream) {
  const float* x     = (const float*)d_in[0];
  const float* wl    = (const float*)d_in[1];
  const float* means = (const float*)d_in[2];
  const float* lv    = (const float*)d_in[3];
  float* out  = (float*)d_out;
  float* part = (float*)d_ws;               // 32*8192 floats = 1 MB
  float* msep = part + NJB * NPTS;          // 32 floats

  fused_kernel<<<dim3(NIB * NJB), dim3(IBLK), 0, stream>>>(
      x, wl, means, lv, part, msep, out);
}

// Round 5
// 71.389 us; speedup vs baseline: 1.9597x; 1.1554x over previous
//
#include <hip/hip_runtime.h>
#include <math.h>

#ifndef M_PI
#define M_PI 3.14159265358979323846
#endif

#define NPTS 8192
#define KCOMP 64
#define JT 256            // j-tile per K1 block
#define IBLK 256          // i's per K1 block (= block size)
#define NJB (NPTS / JT)   // 32 j-chunks
#define NIB (NPTS / IBLK) // 32 i-chunks

// Force the single-instruction hardware exp2 (v_exp_f32, ~1 ulp).
__device__ __forceinline__ float fexp2(float a) {
#if __has_builtin(__builtin_amdgcn_exp2f)
  return __builtin_amdgcn_exp2f(a);
#else
  float r;
  asm("v_exp_f32 %0, %1" : "=v"(r) : "v"(a));
  return r;
#endif
}

// --- K1: pairwise KDE partial sums (67.1M hardware exp2, trans-pipe bound) --
// block(ib,jb): 256 threads, one i each, loops the 256-j LDS tile.
// Atomic-free: partial for (i, jb) -> part[jb*NPTS + i].
// Also zeroes out[0] (K2's atomic target) — kernel boundary makes it safe.
__global__ __launch_bounds__(IBLK, 4) void kde_kernel(
    const float* __restrict__ x,
    float* __restrict__ part,
    float* __restrict__ out) {
  __shared__ alignas(16) float xs[JT];
  // kern = exp(-0.5 d^2 / bw^2) = 2^(-(s*d)^2), s = sqrt(8192 * log2(e))
  const float s = sqrtf(8192.0f * 1.44269504088896340736f);
  const int t  = threadIdx.x;
  const int ib = blockIdx.x;
  const int jb = blockIdx.y;
  const int i  = ib * IBLK + t;
  xs[t] = x[jb * JT + t] * s;     // pre-scaled j-tile
  float u = x[i] * s;             // pre-scaled own point
  if ((ib | jb | t) == 0) out[0] = 0.0f;
  __syncthreads();

  float acc0 = 0.f, acc1 = 0.f, acc2 = 0.f, acc3 = 0.f;
  const float4* xs4 = reinterpret_cast<const float4*>(xs);
#pragma unroll 4
  for (int jj = 0; jj < JT / 4; ++jj) {
    float4 v = xs4[jj];           // ds_read_b128, same-address broadcast
    float d0 = u - v.x;
    float d1 = u - v.y;
    float d2 = u - v.z;
    float d3 = u - v.w;
    acc0 += fexp2(-(d0 * d0));    // v_sub + v_mul + v_exp(-src) + v_add
    acc1 += fexp2(-(d1 * d1));
    acc2 += fexp2(-(d2 * d2));
    acc3 += fexp2(-(d3 * d3));
  }
  part[jb * NPTS + i] = (acc0 + acc1) + (acc2 + acc3);
}

// --- K2: fold partials + softmax + mixture pdf + MSE reduction -------------
__global__ __launch_bounds__(256) void final_kernel(
    const float* __restrict__ x,
    const float* __restrict__ logits,
    const float* __restrict__ means,
    const float* __restrict__ log_vars,
    const float* __restrict__ part,
    float* __restrict__ out) {
  __shared__ float sm[KCOMP], sa[KCOMP], sq[KCOMP], wsum[4];
  const int t = threadIdx.x;
  if (t < KCOMP) {                // wave 0: softmax over K=64 via shfl
    float l = logits[t];
    float m = l;
#pragma unroll
    for (int off = 32; off > 0; off >>= 1)
      m = fmaxf(m, __shfl_xor(m, off));
    float e = expf(l - m);
    float ssum = e;
#pragma unroll
    for (int off = 32; off > 0; off >>= 1)
      ssum += __shfl_xor(ssum, off);
    float w = e / ssum;
    float var = expf(log_vars[t]);
    sm[t] = means[t];
    sa[t] = w * rsqrtf(2.0f * (float)M_PI * var);   // amplitude
    sq[t] = 0.72134752044448170368f / var;          // 0.5*log2(e)/var
  }
  __syncthreads();

  const int i = blockIdx.x * 256 + t;
  // fold the 32 j-chunk partials; 4 independent chains pipeline the L2 loads
  float f0 = 0.f, f1 = 0.f, f2 = 0.f, f3 = 0.f;
#pragma unroll
  for (int jb = 0; jb < NJB; jb += 4) {
    f0 += part[(jb + 0) * NPTS + i];
    f1 += part[(jb + 1) * NPTS + i];
    f2 += part[(jb + 2) * NPTS + i];
    f3 += part[(jb + 3) * NPTS + i];
  }
  float ds = (f0 + f1) + (f2 + f3);
  // data_pdf = ds / (sqrt(2*pi)*bw*N), bw*N = 64
  const float inv_norm = 1.0f / (2.50662827463100050242f * 64.0f);
  float data = ds * inv_norm;

  const float xi = x[i];
  float mix = 0.f;
#pragma unroll 8
  for (int k = 0; k < KCOMP; ++k) {
    float d = xi - sm[k];
    mix += sa[k] * fexp2(-(sq[k] * d) * d);
  }

  float diff = mix - data;
  float v = diff * diff;
#pragma unroll
  for (int off = 32; off > 0; off >>= 1)
    v += __shfl_xor(v, off);
  if ((t & 63) == 0) wsum[t >> 6] = v;
  __syncthreads();
  if (t == 0) atomicAdd(out, (wsum[0] + wsum[1]) + (wsum[2] + wsum[3]));
}

extern "C" void kernel_launch(void* const* d_in, const int* in_sizes, int n_in,
                              void* d_out, int out_size, void* d_ws, size_t ws_size,
                              hipStream_t stream) {
  const float* x     = (const float*)d_in[0];
  const float* wl    = (const float*)d_in[1];
  const float* means = (const float*)d_in[2];
  const float* lv    = (const float*)d_in[3];
  float* out  = (float*)d_out;
  float* part = (float*)d_ws;   // 32 * 8192 floats = 1 MB, fully overwritten by K1

  kde_kernel<<<dim3(NIB, NJB), IBLK, 0, stream>>>(x, part, out);
  final_kernel<<<NPTS / 256, 256, 0, stream>>>(x, wl, means, lv, part, out);
}